// Round 4
// baseline (45994.498 us; speedup 1.0000x reference)
//
#include <hip/hip_runtime.h>

// ============================================================================
// GRUTimeSeries (B=256,T=512,H=512,OUT=256) — round 4: fp32 ANCHOR (bisection)
// Plain per-step kernels (513 launches), pure fp32 VALU, h in global double
// buffers, zero custom sync. Purpose: isolate algorithm/interface correctness
// from the fast-pipeline engineering. Slow by design (~6-9 ms predicted).
// ============================================================================

#define HSLOT 131072  // 256*512 floats per h slot

__device__ __forceinline__ float sig_(float v) { return 1.0f / (1.0f + expf(-v)); }

__global__ __launch_bounds__(256) void ws_zero_v3(float* __restrict__ h) {
  int i = blockIdx.x * 256 + threadIdx.x;
  for (; i < 4 * HSLOT; i += gridDim.x * 256) h[i] = 0.f;
}

// grid = 512 blocks x 256 threads.
//   blocks [0,256):  layer-0 step t   (skipped when t==512)
//   blocks [256,512): layer-1 step t-1 (skipped when t==0)
// Block (bt,dt): batch rows bt*16..+16, hidden dims dt*32..+32.
// Thread (bb = tid&15, dj = tid>>4): batch row bt*16+bb, dims {dj, dj+16}.
// h slots: h(t) lives in slot t&1.
__global__ __launch_bounds__(256) void gru_step_v3(
    const float* __restrict__ x,
    const float* __restrict__ Wih0, const float* __restrict__ bih0,
    const float* __restrict__ Whh0, const float* __restrict__ bhh0,
    const float* __restrict__ Wih1, const float* __restrict__ bih1,
    const float* __restrict__ Whh1, const float* __restrict__ bhh1,
    float* __restrict__ h0, float* __restrict__ h1, const int t)
{
  __shared__ float4 hs4[4096];  // [tile(2)][k4(128)][bb(16)] transposed: bank-safe
  const int tid = threadIdx.x;
  const int bb = tid & 15, dj = tid >> 4;
  const bool isL1 = blockIdx.x >= 256;
  const int blk = isL1 ? (int)blockIdx.x - 256 : (int)blockIdx.x;
  const int bt = blk & 15, dt = blk >> 4;
  if (!isL1 && t >= 512) return;
  if (isL1 && t < 1) return;
  const int b = bt * 16 + bb;
  const int d0 = dt * 32 + dj;

  if (!isL1) {
    // ---- stage h0(t-1) tile (slot (t-1)&1 == (t+1)&1), transposed
    const float* src = h0 + (size_t)((t + 1) & 1) * HSLOT + (size_t)(bt * 16) * 512;
    for (int u = tid; u < 2048; u += 256) {
      const int row = u >> 7, c = u & 127;
      hs4[c * 16 + row] = ((const float4*)(src + (size_t)row * 512))[c];
    }
    __syncthreads();

    const float xv = x[(size_t)b * 512 + t];
    float ar0 = 0.f, az0 = 0.f, an0 = 0.f, ar1 = 0.f, az1 = 0.f, an1 = 0.f;
    const float4* wr0 = (const float4*)(Whh0 + (size_t)d0 * 512);
    const float4* wz0 = (const float4*)(Whh0 + (size_t)(512 + d0) * 512);
    const float4* wn0 = (const float4*)(Whh0 + (size_t)(1024 + d0) * 512);
    const float4* wr1 = (const float4*)(Whh0 + (size_t)(d0 + 16) * 512);
    const float4* wz1 = (const float4*)(Whh0 + (size_t)(528 + d0) * 512);
    const float4* wn1 = (const float4*)(Whh0 + (size_t)(1040 + d0) * 512);
    #pragma unroll 4
    for (int k4 = 0; k4 < 128; ++k4) {
      const float4 hv = hs4[k4 * 16 + bb];
      float4 w;
      w = wr0[k4]; ar0 += hv.x*w.x + hv.y*w.y + hv.z*w.z + hv.w*w.w;
      w = wz0[k4]; az0 += hv.x*w.x + hv.y*w.y + hv.z*w.z + hv.w*w.w;
      w = wn0[k4]; an0 += hv.x*w.x + hv.y*w.y + hv.z*w.z + hv.w*w.w;
      w = wr1[k4]; ar1 += hv.x*w.x + hv.y*w.y + hv.z*w.z + hv.w*w.w;
      w = wz1[k4]; az1 += hv.x*w.x + hv.y*w.y + hv.z*w.z + hv.w*w.w;
      w = wn1[k4]; an1 += hv.x*w.x + hv.y*w.y + hv.z*w.z + hv.w*w.w;
    }
    float arr[2] = {ar0, ar1}, azz[2] = {az0, az1}, ann[2] = {an0, an1};
    #pragma unroll
    for (int e = 0; e < 2; ++e) {
      const int d = d0 + e * 16;
      const float xr = xv * Wih0[d]        + bih0[d];
      const float xz = xv * Wih0[512 + d]  + bih0[512 + d];
      const float xn = xv * Wih0[1024 + d] + bih0[1024 + d];
      const float gr = arr[e] + bhh0[d];
      const float gz = azz[e] + bhh0[512 + d];
      const float gn = ann[e] + bhh0[1024 + d];
      const float r = sig_(xr + gr);
      const float z = sig_(xz + gz);
      const float n = tanhf(xn + r * gn);
      const float hprev = ((const float*)&hs4[(d >> 2) * 16 + bb])[d & 3];
      const float hnew = (1.f - z) * n + z * hprev;
      h0[(size_t)(t & 1) * HSLOT + (size_t)b * 512 + d] = hnew;
    }
  } else {
    const int s = t - 1;  // layer-1 time index
    // ---- stage h0(s) (slot s&1) into tile0, h1(s-1) (slot (s-1)&1 == t&1) into tile1
    const float* src0 = h0 + (size_t)(s & 1) * HSLOT + (size_t)(bt * 16) * 512;
    const float* src1 = h1 + (size_t)(t & 1) * HSLOT + (size_t)(bt * 16) * 512;
    for (int u = tid; u < 4096; u += 256) {
      const int tile = u >> 11, row = (u >> 7) & 15, c = u & 127;
      const float* src = tile ? src1 : src0;
      hs4[tile * 2048 + c * 16 + row] = ((const float4*)(src + (size_t)row * 512))[c];
    }
    __syncthreads();

    float xr0=0.f,xz0=0.f,xn0=0.f,xr1=0.f,xz1=0.f,xn1=0.f;
    float hr0=0.f,hz0=0.f,hn0=0.f,hr1=0.f,hz1=0.f,hn1=0.f;
    const float4* ir0 = (const float4*)(Wih1 + (size_t)d0 * 512);
    const float4* iz0 = (const float4*)(Wih1 + (size_t)(512 + d0) * 512);
    const float4* in0 = (const float4*)(Wih1 + (size_t)(1024 + d0) * 512);
    const float4* ir1 = (const float4*)(Wih1 + (size_t)(d0 + 16) * 512);
    const float4* iz1 = (const float4*)(Wih1 + (size_t)(528 + d0) * 512);
    const float4* in1 = (const float4*)(Wih1 + (size_t)(1040 + d0) * 512);
    const float4* hr0p = (const float4*)(Whh1 + (size_t)d0 * 512);
    const float4* hz0p = (const float4*)(Whh1 + (size_t)(512 + d0) * 512);
    const float4* hn0p = (const float4*)(Whh1 + (size_t)(1024 + d0) * 512);
    const float4* hr1p = (const float4*)(Whh1 + (size_t)(d0 + 16) * 512);
    const float4* hz1p = (const float4*)(Whh1 + (size_t)(528 + d0) * 512);
    const float4* hn1p = (const float4*)(Whh1 + (size_t)(1040 + d0) * 512);
    #pragma unroll 2
    for (int k4 = 0; k4 < 128; ++k4) {
      const float4 u0 = hs4[k4 * 16 + bb];         // h0(s)
      const float4 u1 = hs4[2048 + k4 * 16 + bb];  // h1(s-1)
      float4 w;
      w = ir0[k4];  xr0 += u0.x*w.x + u0.y*w.y + u0.z*w.z + u0.w*w.w;
      w = iz0[k4];  xz0 += u0.x*w.x + u0.y*w.y + u0.z*w.z + u0.w*w.w;
      w = in0[k4];  xn0 += u0.x*w.x + u0.y*w.y + u0.z*w.z + u0.w*w.w;
      w = ir1[k4];  xr1 += u0.x*w.x + u0.y*w.y + u0.z*w.z + u0.w*w.w;
      w = iz1[k4];  xz1 += u0.x*w.x + u0.y*w.y + u0.z*w.z + u0.w*w.w;
      w = in1[k4];  xn1 += u0.x*w.x + u0.y*w.y + u0.z*w.z + u0.w*w.w;
      w = hr0p[k4]; hr0 += u1.x*w.x + u1.y*w.y + u1.z*w.z + u1.w*w.w;
      w = hz0p[k4]; hz0 += u1.x*w.x + u1.y*w.y + u1.z*w.z + u1.w*w.w;
      w = hn0p[k4]; hn0 += u1.x*w.x + u1.y*w.y + u1.z*w.z + u1.w*w.w;
      w = hr1p[k4]; hr1 += u1.x*w.x + u1.y*w.y + u1.z*w.z + u1.w*w.w;
      w = hz1p[k4]; hz1 += u1.x*w.x + u1.y*w.y + u1.z*w.z + u1.w*w.w;
      w = hn1p[k4]; hn1 += u1.x*w.x + u1.y*w.y + u1.z*w.z + u1.w*w.w;
    }
    float gxr[2] = {xr0, xr1}, gxz[2] = {xz0, xz1}, gxn[2] = {xn0, xn1};
    float ghr[2] = {hr0, hr1}, ghz[2] = {hz0, hz1}, ghn[2] = {hn0, hn1};
    #pragma unroll
    for (int e = 0; e < 2; ++e) {
      const int d = d0 + e * 16;
      const float xr = gxr[e] + bih1[d];
      const float xz = gxz[e] + bih1[512 + d];
      const float xn = gxn[e] + bih1[1024 + d];
      const float gr = ghr[e] + bhh1[d];
      const float gz = ghz[e] + bhh1[512 + d];
      const float gn = ghn[e] + bhh1[1024 + d];
      const float r = sig_(xr + gr);
      const float z = sig_(xz + gz);
      const float n = tanhf(xn + r * gn);
      const float hprev = ((const float*)&hs4[2048 + (d >> 2) * 16 + bb])[d & 3];
      const float hnew = (1.f - z) * n + z * hprev;
      h1[(size_t)(s & 1) * HSLOT + (size_t)b * 512 + d] = hnew;
    }
  }
}

// ---------------- fp32 MLP head: Y[b,j] = act(sum_k X[b,k]*W[j,k] + bias[j])
__global__ __launch_bounds__(256)
void mlp_head_v3(const float* __restrict__ X, const float* __restrict__ W,
                 const float* __restrict__ bias, float* __restrict__ Y,
                 const int N, const int act)
{
  __shared__ float Xs[32][258];
  __shared__ float Ws[8][260];
  const int tid = threadIdx.x;
  const int m0 = blockIdx.x << 5;
  const int j0 = blockIdx.y << 6;
  const int b  = tid >> 3;
  const int jj = tid & 7;
  float acc[8];
  #pragma unroll
  for (int i = 0; i < 8; ++i) acc[i] = 0.f;
  for (int kh = 0; kh < 2; ++kh) {
    __syncthreads();
    for (int u = tid; u < 2048; u += 256) {
      const int row = u >> 6, c4 = u & 63;
      const float4 v = *((const float4*)(X + ((m0 + row) << 9) + (kh << 8)) + c4);
      float* dst = &Xs[row][c4 << 2];
      dst[0] = v.x; dst[1] = v.y; dst[2] = v.z; dst[3] = v.w;
    }
    __syncthreads();
    #pragma unroll
    for (int jg = 0; jg < 8; ++jg) {
      if (jg) __syncthreads();
      for (int u = tid; u < 512; u += 256) {
        const int row = u >> 6, c4 = u & 63;
        const float4 v = *((const float4*)(W + ((j0 + (jg << 3) + row) << 9) + (kh << 8)) + c4);
        float* dst = &Ws[row][c4 << 2];
        dst[0] = v.x; dst[1] = v.y; dst[2] = v.z; dst[3] = v.w;
      }
      __syncthreads();
      float a = 0.f;
      #pragma unroll 8
      for (int k = 0; k < 256; ++k) a += Xs[b][k] * Ws[jj][k];
      acc[jg] += a;
    }
  }
  #pragma unroll
  for (int jg = 0; jg < 8; ++jg) {
    const int j = j0 + (jg << 3) + jj;
    float v = acc[jg] + bias[j];
    v = act ? (1.f / (1.f + __expf(-v))) : fmaxf(v, 0.f);
    Y[(m0 + b) * N + j] = v;
  }
}

extern "C" void kernel_launch(void* const* d_in, const int* in_sizes, int n_in,
                              void* d_out, int out_size, void* d_ws, size_t ws_size,
                              hipStream_t stream) {
  (void)in_sizes; (void)n_in; (void)out_size; (void)ws_size;
  const float* x    = (const float*)d_in[0];
  const float* Wih0 = (const float*)d_in[1];
  const float* Whh0 = (const float*)d_in[2];
  const float* bih0 = (const float*)d_in[3];
  const float* bhh0 = (const float*)d_in[4];
  const float* Wih1 = (const float*)d_in[5];
  const float* Whh1 = (const float*)d_in[6];
  const float* bih1 = (const float*)d_in[7];
  const float* bhh1 = (const float*)d_in[8];
  const float* W1 = (const float*)d_in[9];
  const float* b1 = (const float*)d_in[10];
  const float* W2 = (const float*)d_in[11];
  const float* b2 = (const float*)d_in[12];
  const float* W3 = (const float*)d_in[13];
  const float* b3 = (const float*)d_in[14];

  float* h0 = (float*)d_ws;           // 2 slots
  float* h1 = h0 + 2 * HSLOT;         // 2 slots
  float* y1 = h1 + 2 * HSLOT;         // 256x512
  float* y2 = y1 + HSLOT;             // 256x512   (total ws use: 3 MiB)

  ws_zero_v3<<<64, 256, 0, stream>>>(h0);  // h0+h1, both slots
  for (int t = 0; t <= 512; ++t)
    gru_step_v3<<<512, 256, 0, stream>>>(x, Wih0, bih0, Whh0, bhh0,
                                         Wih1, bih1, Whh1, bhh1, h0, h1, t);
  // final hidden = h1(511), slot 511&1 = 1
  mlp_head_v3<<<dim3(8, 8), 256, 0, stream>>>(h1 + HSLOT, W1, b1, y1, 512, 0);
  mlp_head_v3<<<dim3(8, 8), 256, 0, stream>>>(y1, W2, b2, y2, 512, 0);
  mlp_head_v3<<<dim3(8, 4), 256, 0, stream>>>(y2, W3, b3, (float*)d_out, 256, 1);
}

// Round 5
// 10810.332 us; speedup vs baseline: 4.2547x; 4.2547x over previous
//
#include <hip/hip_runtime.h>

// ============================================================================
// GRUTimeSeries (B=256,T=512,H=512,OUT=256) — round 5: per-step MFMA bisection
// Keep anchor's 513-launch structure (kernel-boundary sync = bulletproof),
// replace inner math with the f16 MFMA + swizzled-LDS path from rounds 0-2.
// L0 blocks: 64 batch x 16 dims; L1 blocks: same tile, two GEMMs (Wih1,Whh1).
// h state fp32 in global double buffers. PASS => sync was the round-0-2 bug.
// ============================================================================

#define HSLOT 131072  // 256*512 floats per h slot

typedef __attribute__((ext_vector_type(8))) _Float16 f16x8;
typedef __attribute__((ext_vector_type(4))) float f32x4;

__device__ __forceinline__ float sig_(float v) { return 1.0f / (1.0f + expf(-v)); }

__global__ __launch_bounds__(256) void ws_zero_v4(float* __restrict__ h) {
  int i = blockIdx.x * 256 + threadIdx.x;
  for (; i < 4 * HSLOT; i += gridDim.x * 256) h[i] = 0.f;
}

// grid = 256 blocks x 256 threads (4 waves).
//   blocks [0,128):  layer-0 step t    (skip at t==512)
//   blocks [128,256): layer-1 step t-1 (skip at t==0)
// Block tile: 64 batch rows (bt in 0..3) x 16 hidden dims (dt in 0..31).
// Wave w: batch rows bt*64 + w*16 .. +16.
// MFMA 16x16x32 f16: A row = lane&15, k = (lane>>4)*8+e;
//                    B col = lane&15, k = (lane>>4)*8+e;
//                    D row = (lane>>4)*4+reg, col = lane&15.
__global__ __launch_bounds__(256) void gru_step_m(
    const float* __restrict__ x,
    const float* __restrict__ Wih0, const float* __restrict__ bih0,
    const float* __restrict__ Whh0, const float* __restrict__ bhh0,
    const float* __restrict__ Wih1, const float* __restrict__ bih1,
    const float* __restrict__ Whh1, const float* __restrict__ bhh1,
    float* __restrict__ h0, float* __restrict__ h1, const int t)
{
  extern __shared__ char lds[];  // B tiles: 48 rows (L0) / 96 rows (L1) x 1024B
  const int tid = threadIdx.x;
  const int w = tid >> 6, lane = tid & 63, l15 = lane & 15, q = lane >> 4;
  const bool isL1 = blockIdx.x >= 128;
  const int bb2 = isL1 ? (int)blockIdx.x - 128 : (int)blockIdx.x;
  const int bt = bb2 & 3, dt = bb2 >> 2;
  if (!isL1 && t >= 512) return;
  if (isL1 && t < 1) return;
  const int m0 = bt * 64;          // batch base of this block
  const int d  = dt * 16 + l15;    // this lane's output dim

  const float* h0prev = h0 + (size_t)((t + 1) & 1) * HSLOT;  // h0(t-1)

  // ---- stage B tiles to LDS as f16, rows [mat*48 + gate*16 + dd] x 512 f16,
  //      16B chunk c8 swizzled: byte = ((c8 ^ (row&7)) << 4); row&7 == dd&7.
  {
    const int NR = isL1 ? 96 : 48;
    for (int u = tid; u < NR * 64; u += 256) {
      const int r = u >> 6, c8 = u & 63;
      const int mat = r >> 6 >= 0 ? (r >= 48 ? 1 : 0) : 0;
      const int rr = r - mat * 48, g3 = rr >> 4, dd = rr & 15;
      const float* W = isL1 ? (mat ? Whh1 : Wih1) : Whh0;
      const float* src = W + (size_t)(g3 * 512 + dt * 16 + dd) * 512 + (c8 << 3);
      const float4 v0 = *(const float4*)src;
      const float4 v1 = *(const float4*)(src + 4);
      f16x8 hv;
      hv[0] = (_Float16)v0.x; hv[1] = (_Float16)v0.y;
      hv[2] = (_Float16)v0.z; hv[3] = (_Float16)v0.w;
      hv[4] = (_Float16)v1.x; hv[5] = (_Float16)v1.y;
      hv[6] = (_Float16)v1.z; hv[7] = (_Float16)v1.w;
      *(f16x8*)(lds + (r << 10) + ((c8 ^ (r & 7)) << 4)) = hv;
    }
  }
  __syncthreads();

  f32x4 acc[6];
  #pragma unroll
  for (int i = 0; i < 6; ++i) acc[i] = (f32x4){0.f, 0.f, 0.f, 0.f};

  const float* h1prev = h1 + (size_t)(t & 1) * HSLOT;  // h1(t-2) (L1 only)
  const size_t arow = (size_t)(m0 + w * 16 + l15) * 512 + (q << 3);

  #pragma unroll
  for (int half = 0; half < 2; ++half) {
    f16x8 a0[8], a1[8];
    #pragma unroll
    for (int kc2 = 0; kc2 < 8; ++kc2) {
      const int kc = half * 8 + kc2;
      const float* ap0 = h0prev + arow + kc * 32;
      const float4 u0 = *(const float4*)ap0, u1 = *(const float4*)(ap0 + 4);
      a0[kc2][0] = (_Float16)u0.x; a0[kc2][1] = (_Float16)u0.y;
      a0[kc2][2] = (_Float16)u0.z; a0[kc2][3] = (_Float16)u0.w;
      a0[kc2][4] = (_Float16)u1.x; a0[kc2][5] = (_Float16)u1.y;
      a0[kc2][6] = (_Float16)u1.z; a0[kc2][7] = (_Float16)u1.w;
      if (isL1) {
        const float* ap1 = h1prev + arow + kc * 32;
        const float4 v0 = *(const float4*)ap1, v1 = *(const float4*)(ap1 + 4);
        a1[kc2][0] = (_Float16)v0.x; a1[kc2][1] = (_Float16)v0.y;
        a1[kc2][2] = (_Float16)v0.z; a1[kc2][3] = (_Float16)v0.w;
        a1[kc2][4] = (_Float16)v1.x; a1[kc2][5] = (_Float16)v1.y;
        a1[kc2][6] = (_Float16)v1.z; a1[kc2][7] = (_Float16)v1.w;
      }
    }
    #pragma unroll
    for (int kc2 = 0; kc2 < 8; ++kc2) {
      const int kc = half * 8 + kc2;
      const int bb = ((kc << 6) + (q << 4)) ^ ((l15 & 7) << 4);
      #pragma unroll
      for (int g3 = 0; g3 < 3; ++g3) {
        const f16x8 bf = *(const f16x8*)(lds + ((g3 * 16 + l15) << 10) + bb);
        acc[g3] = __builtin_amdgcn_mfma_f32_16x16x32_f16(a0[kc2], bf, acc[g3], 0, 0, 0);
      }
      if (isL1) {
        #pragma unroll
        for (int g3 = 0; g3 < 3; ++g3) {
          const f16x8 bf = *(const f16x8*)(lds + 49152 + ((g3 * 16 + l15) << 10) + bb);
          acc[3 + g3] = __builtin_amdgcn_mfma_f32_16x16x32_f16(a1[kc2], bf, acc[3 + g3], 0, 0, 0);
        }
      }
    }
  }

  // ---- pointwise gate math + h update (D row = q*4+j, col = l15)
  if (!isL1) {
    const float wxr = Wih0[d], wxz = Wih0[512 + d], wxn = Wih0[1024 + d];
    const float bxr = bih0[d], bxz = bih0[512 + d], bxn = bih0[1024 + d];
    const float bhr = bhh0[d], bhz = bhh0[512 + d], bhn = bhh0[1024 + d];
    float* hdst = h0 + (size_t)(t & 1) * HSLOT;
    #pragma unroll
    for (int j = 0; j < 4; ++j) {
      const int b = m0 + w * 16 + q * 4 + j;
      const float xv = x[(size_t)b * 512 + t];
      const float hp = h0prev[(size_t)b * 512 + d];
      const float r = sig_(xv * wxr + bxr + acc[0][j] + bhr);
      const float z = sig_(xv * wxz + bxz + acc[1][j] + bhz);
      const float n = tanhf(xv * wxn + bxn + r * (acc[2][j] + bhn));
      hdst[(size_t)b * 512 + d] = (1.f - z) * n + z * hp;
    }
  } else {
    const float bxr = bih1[d], bxz = bih1[512 + d], bxn = bih1[1024 + d];
    const float bhr = bhh1[d], bhz = bhh1[512 + d], bhn = bhh1[1024 + d];
    float* hdst = h1 + (size_t)((t + 1) & 1) * HSLOT;  // h1(t-1), slot (t-1)&1
    #pragma unroll
    for (int j = 0; j < 4; ++j) {
      const int b = m0 + w * 16 + q * 4 + j;
      const float hp = h1prev[(size_t)b * 512 + d];
      const float r = sig_(acc[0][j] + bxr + acc[3][j] + bhr);
      const float z = sig_(acc[1][j] + bxz + acc[4][j] + bhz);
      const float n = tanhf(acc[2][j] + bxn + r * (acc[5][j] + bhn));
      hdst[(size_t)b * 512 + d] = (1.f - z) * n + z * hp;
    }
  }
}

// ---------------- fp32 MLP head: Y[b,j] = act(sum_k X[b,k]*W[j,k] + bias[j])
__global__ __launch_bounds__(256)
void mlp_head_v4(const float* __restrict__ X, const float* __restrict__ W,
                 const float* __restrict__ bias, float* __restrict__ Y,
                 const int N, const int act)
{
  __shared__ float Xs[32][258];
  __shared__ float Ws[8][260];
  const int tid = threadIdx.x;
  const int m0 = blockIdx.x << 5;
  const int j0 = blockIdx.y << 6;
  const int b  = tid >> 3;
  const int jj = tid & 7;
  float acc[8];
  #pragma unroll
  for (int i = 0; i < 8; ++i) acc[i] = 0.f;
  for (int kh = 0; kh < 2; ++kh) {
    __syncthreads();
    for (int u = tid; u < 2048; u += 256) {
      const int row = u >> 6, c4 = u & 63;
      const float4 v = *((const float4*)(X + ((m0 + row) << 9) + (kh << 8)) + c4);
      float* dst = &Xs[row][c4 << 2];
      dst[0] = v.x; dst[1] = v.y; dst[2] = v.z; dst[3] = v.w;
    }
    __syncthreads();
    #pragma unroll
    for (int jg = 0; jg < 8; ++jg) {
      if (jg) __syncthreads();
      for (int u = tid; u < 512; u += 256) {
        const int row = u >> 6, c4 = u & 63;
        const float4 v = *((const float4*)(W + ((j0 + (jg << 3) + row) << 9) + (kh << 8)) + c4);
        float* dst = &Ws[row][c4 << 2];
        dst[0] = v.x; dst[1] = v.y; dst[2] = v.z; dst[3] = v.w;
      }
      __syncthreads();
      float a = 0.f;
      #pragma unroll 8
      for (int k = 0; k < 256; ++k) a += Xs[b][k] * Ws[jj][k];
      acc[jg] += a;
    }
  }
  #pragma unroll
  for (int jg = 0; jg < 8; ++jg) {
    const int j = j0 + (jg << 3) + jj;
    float v = acc[jg] + bias[j];
    v = act ? (1.f / (1.f + __expf(-v))) : fmaxf(v, 0.f);
    Y[(m0 + b) * N + j] = v;
  }
}

extern "C" void kernel_launch(void* const* d_in, const int* in_sizes, int n_in,
                              void* d_out, int out_size, void* d_ws, size_t ws_size,
                              hipStream_t stream) {
  (void)in_sizes; (void)n_in; (void)out_size; (void)ws_size;
  const float* x    = (const float*)d_in[0];
  const float* Wih0 = (const float*)d_in[1];
  const float* Whh0 = (const float*)d_in[2];
  const float* bih0 = (const float*)d_in[3];
  const float* bhh0 = (const float*)d_in[4];
  const float* Wih1 = (const float*)d_in[5];
  const float* Whh1 = (const float*)d_in[6];
  const float* bih1 = (const float*)d_in[7];
  const float* bhh1 = (const float*)d_in[8];
  const float* W1 = (const float*)d_in[9];
  const float* b1 = (const float*)d_in[10];
  const float* W2 = (const float*)d_in[11];
  const float* b2 = (const float*)d_in[12];
  const float* W3 = (const float*)d_in[13];
  const float* b3 = (const float*)d_in[14];

  float* h0 = (float*)d_ws;           // 2 slots
  float* h1 = h0 + 2 * HSLOT;         // 2 slots
  float* y1 = h1 + 2 * HSLOT;         // 256x512
  float* y2 = y1 + HSLOT;             // 256x512   (total ws use: 3 MiB)

  hipFuncSetAttribute((const void*)gru_step_m,
                      hipFuncAttributeMaxDynamicSharedMemorySize, 98304);

  ws_zero_v4<<<64, 256, 0, stream>>>(h0);  // h0+h1, both slots
  for (int t = 0; t <= 512; ++t)
    gru_step_m<<<256, 256, 98304, stream>>>(x, Wih0, bih0, Whh0, bhh0,
                                            Wih1, bih1, Whh1, bhh1, h0, h1, t);
  // final hidden = h1(511), slot 511&1 = 1
  mlp_head_v4<<<dim3(8, 8), 256, 0, stream>>>(h1 + HSLOT, W1, b1, y1, 512, 0);
  mlp_head_v4<<<dim3(8, 8), 256, 0, stream>>>(y1, W2, b2, y2, 512, 0);
  mlp_head_v4<<<dim3(8, 4), 256, 0, stream>>>(y2, W3, b3, (float*)d_out, 256, 1);
}